// Round 3
// baseline (25723.303 us; speedup 1.0000x reference)
//
#include <hip/hip_runtime.h>
#include <hip/hip_bf16.h>
#include <stdint.h>

#define SEQ   1024
#define NB    4
#define BT    4096   // NB*SEQ rows
#define DM    512
#define DI    1024

typedef float  f32x4  __attribute__((ext_vector_type(4)));
typedef float  f32x2  __attribute__((ext_vector_type(2)));
typedef short  bf16x8 __attribute__((ext_vector_type(8)));

__device__ __forceinline__ float bf2f(unsigned short u){
  union { unsigned int i; float f; } v; v.i = ((unsigned int)u) << 16; return v.f;
}
__device__ __forceinline__ unsigned short f2bf(float f){
  union { float f; unsigned int i; } v; v.f = f;
  unsigned int x = v.i;
  return (unsigned short)((x + 0x7fffu + ((x >> 16) & 1u)) >> 16);
}
__device__ __forceinline__ float bits2f(uint32_t u){
  union { uint32_t i; float f; } v; v.i = u; return v.f;
}
__device__ __forceinline__ uint32_t f2bits(float f){
  union { float f; uint32_t i; } v; v.f = f; return v.i;
}
__device__ __forceinline__ float sigmoidf_(float x){ return __fdividef(1.f, 1.f + __expf(-x)); }
__device__ __forceinline__ float siluf_(float x){ return x * __fdividef(1.f, 1.f + __expf(-x)); }
__device__ __forceinline__ float tanhf_(float x){
  float e = __expf(2.f*x);
  return 1.f - __fdividef(2.f, e + 1.f);
}

// ---------------- fp32 -> bf16 weight conversion ----------------
__global__ __launch_bounds__(256) void cvt_kernel(const float* __restrict__ in,
                                                  unsigned short* __restrict__ out, int n){
  int i = blockIdx.x*256 + threadIdx.x;
  int stride = gridDim.x*256;
  for (; i < n; i += stride) out[i] = f2bf(in[i]);
}

// ---------------- fused residual-add + layernorm ----------------
__global__ __launch_bounds__(256) void ln_kernel(
    const float* __restrict__ hidden, const float* __restrict__ resid_in,
    const float* __restrict__ gamma,  const float* __restrict__ beta,
    float* __restrict__ resid_out, unsigned short* __restrict__ out_bf,
    float* __restrict__ out_f32)
{
  int wave = threadIdx.x >> 6;
  int lane = threadIdx.x & 63;
  int row  = blockIdx.x*4 + wave;               // 4096 rows
  size_t base = (size_t)row * DM + lane*8;
  float4 a0 = *(const float4*)(hidden + base);
  float4 a1 = *(const float4*)(hidden + base + 4);
  if (resid_in){
    float4 b0 = *(const float4*)(resid_in + base);
    float4 b1 = *(const float4*)(resid_in + base + 4);
    a0.x+=b0.x; a0.y+=b0.y; a0.z+=b0.z; a0.w+=b0.w;
    a1.x+=b1.x; a1.y+=b1.y; a1.z+=b1.z; a1.w+=b1.w;
  }
  if (resid_out){
    *(float4*)(resid_out + base)     = a0;
    *(float4*)(resid_out + base + 4) = a1;
  }
  float xv[8] = {a0.x,a0.y,a0.z,a0.w,a1.x,a1.y,a1.z,a1.w};
  float s = 0.f, sq = 0.f;
  #pragma unroll
  for (int q=0;q<8;q++){ s += xv[q]; sq += xv[q]*xv[q]; }
  #pragma unroll
  for (int off=32; off; off>>=1){ s += __shfl_xor(s, off); sq += __shfl_xor(sq, off); }
  float mean = s * (1.f/DM);
  float var  = sq * (1.f/DM) - mean*mean;
  float rstd = rsqrtf(var + 1e-5f);
  float4 g0 = *(const float4*)(gamma + lane*8);
  float4 g1 = *(const float4*)(gamma + lane*8 + 4);
  float4 e0 = *(const float4*)(beta  + lane*8);
  float4 e1 = *(const float4*)(beta  + lane*8 + 4);
  float gv[8] = {g0.x,g0.y,g0.z,g0.w,g1.x,g1.y,g1.z,g1.w};
  float ev[8] = {e0.x,e0.y,e0.z,e0.w,e1.x,e1.y,e1.z,e1.w};
  float yv[8];
  #pragma unroll
  for (int q=0;q<8;q++) yv[q] = (xv[q]-mean)*rstd*gv[q] + ev[q];
  if (out_bf){
    uint4 p;
    p.x = (unsigned)f2bf(yv[0]) | ((unsigned)f2bf(yv[1])<<16);
    p.y = (unsigned)f2bf(yv[2]) | ((unsigned)f2bf(yv[3])<<16);
    p.z = (unsigned)f2bf(yv[4]) | ((unsigned)f2bf(yv[5])<<16);
    p.w = (unsigned)f2bf(yv[6]) | ((unsigned)f2bf(yv[7])<<16);
    *(uint4*)(out_bf + base) = p;
  }
  if (out_f32){
    float4 o0 = {yv[0],yv[1],yv[2],yv[3]};
    float4 o1 = {yv[4],yv[5],yv[6],yv[7]};
    *(float4*)(out_f32 + base)     = o0;
    *(float4*)(out_f32 + base + 4) = o1;
  }
}

// ---------------- bf16 MFMA GEMM:  C[M,N] = A[M,K] * B[N,K]^T + bias ----------------
__global__ __launch_bounds__(256) void gemm_kernel(
    const unsigned short* __restrict__ A, const unsigned short* __restrict__ B,
    const float* __restrict__ bias,
    float* __restrict__ Cf, unsigned short* __restrict__ Cbf,
    int M, int N, int K)
{
  int tid  = threadIdx.x;
  int wid  = tid >> 6, lane = tid & 63;
  int wm   = wid >> 1, wn = wid & 1;
  int tm   = blockIdx.y*128 + wm*64;
  int tn   = blockIdx.x*128 + wn*64;
  int l15  = lane & 15;
  int lk   = (lane >> 4) * 8;

  f32x4 acc[4][4] = {};
  for (int kk = 0; kk < K; kk += 32){
    bf16x8 a[4], b[4];
    #pragma unroll
    for (int f=0; f<4; ++f)
      a[f] = *(const bf16x8*)(A + (size_t)(tm + f*16 + l15)*K + kk + lk);
    #pragma unroll
    for (int f=0; f<4; ++f)
      b[f] = *(const bf16x8*)(B + (size_t)(tn + f*16 + l15)*K + kk + lk);
    #pragma unroll
    for (int i=0;i<4;i++)
      #pragma unroll
      for (int j=0;j<4;j++)
        acc[i][j] = __builtin_amdgcn_mfma_f32_16x16x32_bf16(a[i], b[j], acc[i][j], 0,0,0);
  }
  int crow0 = (lane>>4)*4;
  #pragma unroll
  for (int i=0;i<4;i++){
    #pragma unroll
    for (int j=0;j<4;j++){
      int col = tn + j*16 + l15;
      float bv = bias ? bias[col] : 0.f;
      #pragma unroll
      for (int r=0;r<4;r++){
        int row = tm + i*16 + crow0 + r;
        float val = acc[i][j][r] + bv;
        if (Cf)  Cf [(size_t)row*N + col] = val;
        else     Cbf[(size_t)row*N + col] = f2bf(val);
      }
    }
  }
}

// ---------------- causal depthwise conv(4) + SiLU ----------------
__global__ __launch_bounds__(256) void conv_silu_kernel(
  const float* __restrict__ xz, const float* __restrict__ cw, const float* __restrict__ cb,
  unsigned short* __restrict__ xconv)
{
  int idx = blockIdx.x*256 + threadIdx.x;       // < 4*1024*1024
  int c = idx & (DI-1);
  int t = (idx >> 10) & (SEQ-1);
  const float* base = xz + (size_t)(idx >> 10) * (2*DI) + c;
  float w0 = cw[c*4+0], w1 = cw[c*4+1], w2 = cw[c*4+2], w3 = cw[c*4+3];
  float acc = cb[c] + base[0] * w3;
  if (t >= 1) acc += base[-(2*DI)]   * w2;
  if (t >= 2) acc += base[-(4*DI)]   * w1;
  if (t >= 3) acc += base[-(6*DI)]   * w0;
  xconv[idx] = f2bf(siluf_(acc));
}

// ---------------- persistent GRU scan (tagged-h sync) ----------------
// 256 wgs x 512 thr: b = wg>>6, g = wg&63 -> outputs i in [g*16,g*16+16)
// thread: il = tid>>5 (output), ks = tid&31 (32-wide K slice); weights =
// 96 fp32 VGPRs/thread. Sync: h stored as one 8B word {f32 h | u32 tag};
// consumers poll their 2 slots (u64 >= tag<<32), value arrives with the
// tag -> no vmcnt drain, no separate flag, no separate h fetch.
// Parity double-buffered tagged slots + parity LDS; 1 barrier/step.
__global__ __launch_bounds__(512, 1) void scan_kernel(
    const unsigned short* __restrict__ xih,   // [BT,3*DI] bf16 (bih included)
    const float* __restrict__ xz,             // [BT,2*DI] (z at +DI)
    const unsigned short* __restrict__ whh,   // [3*DI,DI] bf16
    const float* __restrict__ bhh,            // [3*DI]
    unsigned long long* __restrict__ hbuf,    // [2][NB][DI] tagged h
    unsigned short* __restrict__ xout,        // [BT,DI] bf16
    int layer)
{
  const int wg  = blockIdx.x;
  const int b   = wg >> 6;
  const int g   = wg & 63;
  const int tid = threadIdx.x;
  const int il  = tid >> 5;
  const int ks  = tid & 31;
  const int i   = g*16 + il;
  const int k0  = ks*32;

  // ---- pre-unpack whh slice to 96 fp32 regs ----
  float wr[32], wz[32], wn[32];
  {
    const uint32_t* pr = (const uint32_t*)(whh + (size_t)i*DI + k0);
    const uint32_t* pz = (const uint32_t*)(whh + (size_t)(DI+i)*DI + k0);
    const uint32_t* pn = (const uint32_t*)(whh + (size_t)(2*DI+i)*DI + k0);
    #pragma unroll
    for (int j=0;j<16;j++){
      uint32_t u = pr[j];
      wr[2*j]   = bits2f(u << 16);
      wr[2*j+1] = bits2f(u & 0xffff0000u);
    }
    #pragma unroll
    for (int j=0;j<16;j++){
      uint32_t u = pz[j];
      wz[2*j]   = bits2f(u << 16);
      wz[2*j+1] = bits2f(u & 0xffff0000u);
    }
    #pragma unroll
    for (int j=0;j<16;j++){
      uint32_t u = pn[j];
      wn[2*j]   = bits2f(u << 16);
      wn[2*j+1] = bits2f(u & 0xffff0000u);
    }
  }
  const float bhr = bhh[i], bhz = bhh[DI+i], bhn = bhh[2*DI+i];

  // stride-34 padded: k -> k + (k>>5)*2  (2-way bank alias only; 8B aligned)
  __shared__ float hsh[2][1088];

  const unsigned int lbase = (unsigned int)layer * 1024u;

  // x regs (gate lanes ks==0 only)
  float xr_c=0.f, xzg_c=0.f, xn_c=0.f, zg_c=0.f;
  float xr_n=0.f, xzg_n=0.f, xn_n=0.f, zg_n=0.f;
  if (ks == 0){
    const size_t r0 = (size_t)b*SEQ;
    xr_c  = bf2f(xih[r0*3*DI + i]);
    xzg_c = bf2f(xih[r0*3*DI + DI + i]);
    xn_c  = bf2f(xih[r0*3*DI + 2*DI + i]);
    zg_c  = xz[r0*2*DI + DI + i];
  }

  for (int t=0; t<SEQ; ++t){
    const int par = t & 1;
    if (t == 0){
      for (int j=tid; j<1088; j+=512) hsh[0][j] = 0.f;
    } else {
      const unsigned long long want = ((unsigned long long)(lbase + (unsigned)t)) << 32;
      const unsigned long long* p = hbuf + ((size_t)par*NB + b)*DI + 2*tid;
      unsigned long long u0 = __hip_atomic_load(p,   __ATOMIC_RELAXED, __HIP_MEMORY_SCOPE_AGENT);
      unsigned long long u1 = __hip_atomic_load(p+1, __ATOMIC_RELAXED, __HIP_MEMORY_SCOPE_AGENT);
      while (u0 < want) u0 = __hip_atomic_load(p,   __ATOMIC_RELAXED, __HIP_MEMORY_SCOPE_AGENT);
      while (u1 < want) u1 = __hip_atomic_load(p+1, __ATOMIC_RELAXED, __HIP_MEMORY_SCOPE_AGENT);
      const int k = 2*tid;
      float* dst = &hsh[par][k + ((k>>5)<<1)];
      f32x2 hv = { bits2f((uint32_t)u0), bits2f((uint32_t)u1) };
      *(f32x2*)dst = hv;
    }
    __syncthreads();     // hsh[par] ready

    // prefetch x(t+1) — hides under dot
    if (ks == 0 && t+1 < SEQ){
      const size_t r1 = (size_t)(b*SEQ + t + 1);
      xr_n  = bf2f(xih[r1*3*DI + i]);
      xzg_n = bf2f(xih[r1*3*DI + DI + i]);
      xn_n  = bf2f(xih[r1*3*DI + 2*DI + i]);
      zg_n  = xz[r1*2*DI + DI + i];
    }

    // ---- dot: 16 x (ds_read_b64 + 6 fma) ----
    float ar=0.f, az=0.f, an=0.f;
    const float* hrow = &hsh[par][ks*34];
    #pragma unroll
    for (int j=0;j<16;j++){
      f32x2 h2 = *(const f32x2*)(hrow + 2*j);
      ar = fmaf(wr[2*j+0], h2.x, ar); az = fmaf(wz[2*j+0], h2.x, az); an = fmaf(wn[2*j+0], h2.x, an);
      ar = fmaf(wr[2*j+1], h2.y, ar); az = fmaf(wz[2*j+1], h2.y, az); an = fmaf(wn[2*j+1], h2.y, an);
    }
    #pragma unroll
    for (int off=1; off<32; off<<=1){
      ar += __shfl_xor(ar, off);
      az += __shfl_xor(az, off);
      an += __shfl_xor(an, off);
    }

    if (ks == 0){
      float r = sigmoidf_(xr_c + ar + bhr);
      float z = sigmoidf_(xzg_c + az + bhz);
      float n = tanhf_(xn_c + r*(an + bhn));
      float hprev = hsh[par][i + ((i>>5)<<1)];
      float hnew  = (1.f - z)*n + z*hprev;
      unsigned long long packed = (unsigned long long)f2bits(hnew)
                                | (((unsigned long long)(lbase + (unsigned)t + 1u)) << 32);
      __hip_atomic_store(hbuf + ((size_t)((t+1)&1)*NB + b)*DI + i, packed,
                         __ATOMIC_RELAXED, __HIP_MEMORY_SCOPE_AGENT);
      const size_t rowx = (size_t)(b*SEQ + t);
      xout[rowx*DI + i] = f2bf(hnew * siluf_(zg_c));
      xr_c = xr_n; xzg_c = xzg_n; xn_c = xn_n; zg_c = zg_n;
    }
  }
}

// ---------------- host ----------------
extern "C" void kernel_launch(void* const* d_in, const int* in_sizes, int n_in,
                              void* d_out, int out_size, void* d_ws, size_t ws_size,
                              hipStream_t stream)
{
  (void)in_sizes; (void)n_in; (void)out_size; (void)ws_size;
  const float* x      = (const float*)d_in[0];
  const float* norm_w = (const float*)d_in[1];
  const float* norm_b = (const float*)d_in[2];
  const float* inw    = (const float*)d_in[3];
  const float* inb    = (const float*)d_in[4];
  const float* convw  = (const float*)d_in[5];
  const float* convb  = (const float*)d_in[6];
  const float* wih    = (const float*)d_in[7];
  const float* whh    = (const float*)d_in[8];
  const float* bih    = (const float*)d_in[9];
  const float* bhh    = (const float*)d_in[10];
  const float* outw   = (const float*)d_in[11];
  const float* outb   = (const float*)d_in[12];
  const float* normfw = (const float*)d_in[13];
  const float* normfb = (const float*)d_in[14];
  float* out = (float*)d_out;

  char* ws = (char*)d_ws;
  size_t off = 0;
  auto alloc = [&](size_t bytes)->void*{ void* p = ws + off; off = (off + bytes + 255) & ~(size_t)255; return p; };
  float*          resid  = (float*)         alloc((size_t)BT*DM*4);
  unsigned short* lnbf   = (unsigned short*)alloc((size_t)BT*DM*2);
  float*          xz     = (float*)         alloc((size_t)BT*2*DI*4);
  unsigned short* xconv  = (unsigned short*)alloc((size_t)BT*DI*2);
  unsigned short* xihb   = (unsigned short*)alloc((size_t)BT*3*DI*2);
  unsigned short* xoutb  = (unsigned short*)alloc((size_t)BT*DI*2);
  float*          hidden = (float*)         alloc((size_t)BT*DM*4);
  unsigned short* w1bf   = (unsigned short*)alloc((size_t)2048*512*2);
  unsigned short* wihbf  = (unsigned short*)alloc((size_t)3072*1024*2);
  unsigned short* whhbf  = (unsigned short*)alloc((size_t)3072*1024*2);
  unsigned short* woutbf = (unsigned short*)alloc((size_t)512*1024*2);
  unsigned long long* hbuf = (unsigned long long*)alloc((size_t)2*NB*DI*8);

  hipMemsetAsync(hbuf, 0, (size_t)2*NB*DI*8, stream);

  const float* hid_in = x;
  const float* res_in = nullptr;
  for (int l = 0; l < 6; ++l){
    ln_kernel<<<1024, 256, 0, stream>>>(hid_in, res_in, norm_w + l*DM, norm_b + l*DM,
                                        resid, lnbf, nullptr);
    cvt_kernel<<<2048, 256, 0, stream>>>(inw  + (size_t)l*2048*512,  w1bf,   2048*512);
    cvt_kernel<<<2048, 256, 0, stream>>>(wih  + (size_t)l*3072*1024, wihbf,  3072*1024);
    cvt_kernel<<<2048, 256, 0, stream>>>(whh  + (size_t)l*3072*1024, whhbf,  3072*1024);
    cvt_kernel<<<2048, 256, 0, stream>>>(outw + (size_t)l*512*1024,  woutbf, 512*1024);
    // in_proj: xz = ln * inw^T + inb   [4096 x 2048], fp32 out
    gemm_kernel<<<dim3(2048/128, BT/128), 256, 0, stream>>>(lnbf, w1bf, inb + l*2048,
                                                            xz, nullptr, BT, 2048, 512);
    conv_silu_kernel<<<(BT*DI)/256, 256, 0, stream>>>(xz, convw + (size_t)l*DI*4,
                                                      convb + (size_t)l*DI, xconv);
    // gru input: xih = xconv * wih^T + bih  [4096 x 3072], bf16 out
    gemm_kernel<<<dim3(3072/128, BT/128), 256, 0, stream>>>(xconv, wihbf, bih + l*3072,
                                                            nullptr, xihb, BT, 3072, 1024);
    scan_kernel<<<256, 512, 0, stream>>>(xihb, xz, whhbf, bhh + l*3072, hbuf, xoutb, l);
    // out proj: hidden = xout * outw^T + outb  [4096 x 512], fp32 out
    gemm_kernel<<<dim3(512/128, BT/128), 256, 0, stream>>>(xoutb, woutbf, outb + l*DM,
                                                           hidden, nullptr, BT, 512, 1024);
    hid_in = hidden; res_in = resid;
  }
  ln_kernel<<<1024, 256, 0, stream>>>(hidden, resid, normfw, normfb,
                                      nullptr, nullptr, out);
}

// Round 5
// 18309.579 us; speedup vs baseline: 1.4049x; 1.4049x over previous
//
#include <hip/hip_runtime.h>
#include <hip/hip_bf16.h>
#include <stdint.h>

#define SEQ   1024
#define NB    4
#define BT    4096   // NB*SEQ rows
#define DM    512
#define DI    1024

typedef float  f32x4  __attribute__((ext_vector_type(4)));
typedef float  f32x2  __attribute__((ext_vector_type(2)));
typedef short  bf16x8 __attribute__((ext_vector_type(8)));
typedef _Float16 f16x2 __attribute__((ext_vector_type(2)));

__device__ __forceinline__ float bf2f(unsigned short u){
  union { unsigned int i; float f; } v; v.i = ((unsigned int)u) << 16; return v.f;
}
__device__ __forceinline__ unsigned short f2bf(float f){
  union { float f; unsigned int i; } v; v.f = f;
  unsigned int x = v.i;
  return (unsigned short)((x + 0x7fffu + ((x >> 16) & 1u)) >> 16);
}
__device__ __forceinline__ float bits2f(uint32_t u){
  union { uint32_t i; float f; } v; v.i = u; return v.f;
}
__device__ __forceinline__ uint32_t f2bits(float f){
  union { float f; uint32_t i; } v; v.f = f; return v.i;
}
__device__ __forceinline__ f16x2 u2h(uint32_t u){
  union { uint32_t u; f16x2 h; } v; v.u = u; return v.h;
}
// cvt_pkrtz returns __fp16-vector; bit-cast to u32 through a union
__device__ __forceinline__ uint32_t pkrtz2u(float a, float b){
  union { __fp16 __attribute__((ext_vector_type(2))) h; uint32_t u; } v;
  v.h = __builtin_amdgcn_cvt_pkrtz(a, b);
  return v.u;
}
__device__ __forceinline__ float sigmoidf_(float x){ return __fdividef(1.f, 1.f + __expf(-x)); }
__device__ __forceinline__ float siluf_(float x){ return x * __fdividef(1.f, 1.f + __expf(-x)); }
__device__ __forceinline__ float tanhf_(float x){
  float e = __expf(2.f*x);
  return 1.f - __fdividef(2.f, e + 1.f);
}

// ---------------- fp32 -> bf16 weight conversion ----------------
__global__ __launch_bounds__(256) void cvt_kernel(const float* __restrict__ in,
                                                  unsigned short* __restrict__ out, int n){
  int i = blockIdx.x*256 + threadIdx.x;
  int stride = gridDim.x*256;
  for (; i < n; i += stride) out[i] = f2bf(in[i]);
}

// ---------------- fp32 -> f16 weight conversion ----------------
__global__ __launch_bounds__(256) void cvt16_kernel(const float* __restrict__ in,
                                                    unsigned short* __restrict__ out, int n){
  int i = blockIdx.x*256 + threadIdx.x;
  int stride = gridDim.x*256;
  for (; i < n; i += stride){
    _Float16 h = (_Float16)in[i];
    union { _Float16 h; unsigned short u; } v; v.h = h;
    out[i] = v.u;
  }
}

// ---------------- fused residual-add + layernorm ----------------
__global__ __launch_bounds__(256) void ln_kernel(
    const float* __restrict__ hidden, const float* __restrict__ resid_in,
    const float* __restrict__ gamma,  const float* __restrict__ beta,
    float* __restrict__ resid_out, unsigned short* __restrict__ out_bf,
    float* __restrict__ out_f32)
{
  int wave = threadIdx.x >> 6;
  int lane = threadIdx.x & 63;
  int row  = blockIdx.x*4 + wave;               // 4096 rows
  size_t base = (size_t)row * DM + lane*8;
  float4 a0 = *(const float4*)(hidden + base);
  float4 a1 = *(const float4*)(hidden + base + 4);
  if (resid_in){
    float4 b0 = *(const float4*)(resid_in + base);
    float4 b1 = *(const float4*)(resid_in + base + 4);
    a0.x+=b0.x; a0.y+=b0.y; a0.z+=b0.z; a0.w+=b0.w;
    a1.x+=b1.x; a1.y+=b1.y; a1.z+=b1.z; a1.w+=b1.w;
  }
  if (resid_out){
    *(float4*)(resid_out + base)     = a0;
    *(float4*)(resid_out + base + 4) = a1;
  }
  float xv[8] = {a0.x,a0.y,a0.z,a0.w,a1.x,a1.y,a1.z,a1.w};
  float s = 0.f, sq = 0.f;
  #pragma unroll
  for (int q=0;q<8;q++){ s += xv[q]; sq += xv[q]*xv[q]; }
  #pragma unroll
  for (int off=32; off; off>>=1){ s += __shfl_xor(s, off); sq += __shfl_xor(sq, off); }
  float mean = s * (1.f/DM);
  float var  = sq * (1.f/DM) - mean*mean;
  float rstd = rsqrtf(var + 1e-5f);
  float4 g0 = *(const float4*)(gamma + lane*8);
  float4 g1 = *(const float4*)(gamma + lane*8 + 4);
  float4 e0 = *(const float4*)(beta  + lane*8);
  float4 e1 = *(const float4*)(beta  + lane*8 + 4);
  float gv[8] = {g0.x,g0.y,g0.z,g0.w,g1.x,g1.y,g1.z,g1.w};
  float ev[8] = {e0.x,e0.y,e0.z,e0.w,e1.x,e1.y,e1.z,e1.w};
  float yv[8];
  #pragma unroll
  for (int q=0;q<8;q++) yv[q] = (xv[q]-mean)*rstd*gv[q] + ev[q];
  if (out_bf){
    uint4 p;
    p.x = (unsigned)f2bf(yv[0]) | ((unsigned)f2bf(yv[1])<<16);
    p.y = (unsigned)f2bf(yv[2]) | ((unsigned)f2bf(yv[3])<<16);
    p.z = (unsigned)f2bf(yv[4]) | ((unsigned)f2bf(yv[5])<<16);
    p.w = (unsigned)f2bf(yv[6]) | ((unsigned)f2bf(yv[7])<<16);
    *(uint4*)(out_bf + base) = p;
  }
  if (out_f32){
    float4 o0 = {yv[0],yv[1],yv[2],yv[3]};
    float4 o1 = {yv[4],yv[5],yv[6],yv[7]};
    *(float4*)(out_f32 + base)     = o0;
    *(float4*)(out_f32 + base + 4) = o1;
  }
}

// ---------------- bf16 MFMA GEMM:  C[M,N] = A[M,K] * B[N,K]^T + bias ----------------
__global__ __launch_bounds__(256) void gemm_kernel(
    const unsigned short* __restrict__ A, const unsigned short* __restrict__ B,
    const float* __restrict__ bias,
    float* __restrict__ Cf, unsigned short* __restrict__ Cbf,
    int M, int N, int K)
{
  int tid  = threadIdx.x;
  int wid  = tid >> 6, lane = tid & 63;
  int wm   = wid >> 1, wn = wid & 1;
  int tm   = blockIdx.y*128 + wm*64;
  int tn   = blockIdx.x*128 + wn*64;
  int l15  = lane & 15;
  int lk   = (lane >> 4) * 8;

  f32x4 acc[4][4] = {};
  for (int kk = 0; kk < K; kk += 32){
    bf16x8 a[4], b[4];
    #pragma unroll
    for (int f=0; f<4; ++f)
      a[f] = *(const bf16x8*)(A + (size_t)(tm + f*16 + l15)*K + kk + lk);
    #pragma unroll
    for (int f=0; f<4; ++f)
      b[f] = *(const bf16x8*)(B + (size_t)(tn + f*16 + l15)*K + kk + lk);
    #pragma unroll
    for (int i=0;i<4;i++)
      #pragma unroll
      for (int j=0;j<4;j++)
        acc[i][j] = __builtin_amdgcn_mfma_f32_16x16x32_bf16(a[i], b[j], acc[i][j], 0,0,0);
  }
  int crow0 = (lane>>4)*4;
  #pragma unroll
  for (int i=0;i<4;i++){
    #pragma unroll
    for (int j=0;j<4;j++){
      int col = tn + j*16 + l15;
      float bv = bias ? bias[col] : 0.f;
      #pragma unroll
      for (int r=0;r<4;r++){
        int row = tm + i*16 + crow0 + r;
        float val = acc[i][j][r] + bv;
        if (Cf)  Cf [(size_t)row*N + col] = val;
        else     Cbf[(size_t)row*N + col] = f2bf(val);
      }
    }
  }
}

// ---------------- causal depthwise conv(4) + SiLU ----------------
__global__ __launch_bounds__(256) void conv_silu_kernel(
  const float* __restrict__ xz, const float* __restrict__ cw, const float* __restrict__ cb,
  unsigned short* __restrict__ xconv)
{
  int idx = blockIdx.x*256 + threadIdx.x;       // < 4*1024*1024
  int c = idx & (DI-1);
  int t = (idx >> 10) & (SEQ-1);
  const float* base = xz + (size_t)(idx >> 10) * (2*DI) + c;
  float w0 = cw[c*4+0], w1 = cw[c*4+1], w2 = cw[c*4+2], w3 = cw[c*4+3];
  float acc = cb[c] + base[0] * w3;
  if (t >= 1) acc += base[-(2*DI)]   * w2;
  if (t >= 2) acc += base[-(4*DI)]   * w1;
  if (t >= 3) acc += base[-(6*DI)]   * w0;
  xconv[idx] = f2bf(siluf_(acc));
}

// ---------------- persistent GRU scan (tagged-h + sleep backoff + f16 dot) -----
// 256 wgs x 256 thr: b = wg>>6, g = wg&63 -> outputs i in [g*16,g*16+16)
// thread: il = tid>>4 (output), ks = tid&15 (64-wide K slice).
// whh pre-converted to f16; weights stay PACKED (96 u32/thread), dot uses
// v_dot2_f32_f16 -> no unpack, no remat fight with the register allocator.
// Sync: h as {f32,tag} u64, fire-and-forget sc0/sc1 store; all threads poll
// their 4 slots via 2x16B coherent loads with s_sleep backoff; one barrier
// per step (parity LDS + parity hbuf, WAR-safe transitively via barrier).
__global__ __launch_bounds__(256, 1) void scan_kernel(
    const unsigned short* __restrict__ xih,   // [BT,3*DI] bf16 (bih included)
    const float* __restrict__ xz,             // [BT,2*DI] (z at +DI)
    const unsigned short* __restrict__ whh16, // [3*DI,DI] f16
    const float* __restrict__ bhh,            // [3*DI]
    unsigned long long* __restrict__ hbuf,    // [2][NB][DI] tagged h
    unsigned short* __restrict__ xout,        // [BT,DI] bf16
    int layer)
{
  const int wg  = blockIdx.x;
  const int b   = wg >> 6;
  const int g   = wg & 63;
  const int tid = threadIdx.x;
  const int il  = tid >> 4;
  const int ks  = tid & 15;
  const int i   = g*16 + il;
  const int k0  = ks*64;

  // ---- packed f16 weights: 3 x 32 u32 ----
  uint32_t wrp[32], wzp[32], wnp[32];
  {
    const uint32_t* pr = (const uint32_t*)(whh16 + (size_t)i*DI + k0);
    const uint32_t* pz = (const uint32_t*)(whh16 + (size_t)(DI+i)*DI + k0);
    const uint32_t* pn = (const uint32_t*)(whh16 + (size_t)(2*DI+i)*DI + k0);
    #pragma unroll
    for (int j=0;j<32;j++) wrp[j]=pr[j];
    #pragma unroll
    for (int j=0;j<32;j++) wzp[j]=pz[j];
    #pragma unroll
    for (int j=0;j<32;j++) wnp[j]=pn[j];
  }
  const float bhr = bhh[i], bhz = bhh[DI+i], bhn = bhh[2*DI+i];

  // f16-packed h: 16 slices x 32 words, +2 pad words -> bank = 2*ks+2j (distinct)
  __shared__ uint32_t hshw[2][16*34];

  const uint32_t lbase = (uint32_t)layer * 1024u;

  // x regs (gate lanes ks==0 only)
  float xr_c=0.f, xzg_c=0.f, xn_c=0.f, zg_c=0.f;
  float xr_n=0.f, xzg_n=0.f, xn_n=0.f, zg_n=0.f;
  if (ks == 0){
    const size_t r0 = (size_t)b*SEQ;
    xr_c  = bf2f(xih[r0*3*DI + i]);
    xzg_c = bf2f(xih[r0*3*DI + DI + i]);
    xn_c  = bf2f(xih[r0*3*DI + 2*DI + i]);
    zg_c  = xz[r0*2*DI + DI + i];
  }
  float hprev = 0.f;   // gate lane owns output i every step

  for (int t=0; t<SEQ; ++t){
    const int par = t & 1;
    if (t == 0){
      for (int j=tid; j<16*34; j+=256) hshw[0][j] = 0u;
    } else {
      const uint32_t want = lbase + (uint32_t)t;
      const uintptr_t p = (uintptr_t)(hbuf + ((size_t)par*NB + b)*DI + 4*tid);
      uint4 A, B;
      asm volatile("global_load_dwordx4 %0, %2, off sc0 sc1\n\t"
                   "global_load_dwordx4 %1, %3, off sc0 sc1\n\t"
                   "s_waitcnt vmcnt(0)"
                   : "=&v"(A), "=&v"(B)
                   : "v"(p), "v"(p + 32)
                   : "memory");
      while ((A.y < want) | (A.w < want) | (B.y < want) | (B.w < want)){
        __builtin_amdgcn_s_sleep(1);
        asm volatile("global_load_dwordx4 %0, %2, off sc0 sc1\n\t"
                     "global_load_dwordx4 %1, %3, off sc0 sc1\n\t"
                     "s_waitcnt vmcnt(0)"
                     : "=&v"(A), "=&v"(B)
                     : "v"(p), "v"(p + 32)
                     : "memory");
      }
      // pack 4 f32 h -> 2 f16x2 words, write 8B to LDS
      const int kk = 4*tid;
      uint32_t* dst = &hshw[par][(kk>>6)*34 + ((kk & 63) >> 1)];
      uint2 uu; uu.x = pkrtz2u(bits2f(A.x), bits2f(A.z));
      uu.y = pkrtz2u(bits2f(B.x), bits2f(B.z));
      *(uint2*)dst = uu;
    }
    __syncthreads();     // hshw[par] ready

    // prefetch x(t+1) — hides under dot
    if (ks == 0 && t+1 < SEQ){
      const size_t r1 = (size_t)(b*SEQ + t + 1);
      xr_n  = bf2f(xih[r1*3*DI + i]);
      xzg_n = bf2f(xih[r1*3*DI + DI + i]);
      xn_n  = bf2f(xih[r1*3*DI + 2*DI + i]);
      zg_n  = xz[r1*2*DI + DI + i];
    }

    // ---- dot: 16 x (ds_read_b64 + 6 fdot2) ----
    float ar=0.f, az=0.f, an=0.f;
    const uint32_t* hrow = &hshw[par][ks*34];
#if __has_builtin(__builtin_amdgcn_fdot2)
    #pragma unroll
    for (int j=0;j<16;j++){
      uint2 hw = *(const uint2*)(hrow + 2*j);
      f16x2 h0 = u2h(hw.x), h1 = u2h(hw.y);
      ar = __builtin_amdgcn_fdot2(u2h(wrp[2*j]),   h0, ar, false);
      az = __builtin_amdgcn_fdot2(u2h(wzp[2*j]),   h0, az, false);
      an = __builtin_amdgcn_fdot2(u2h(wnp[2*j]),   h0, an, false);
      ar = __builtin_amdgcn_fdot2(u2h(wrp[2*j+1]), h1, ar, false);
      az = __builtin_amdgcn_fdot2(u2h(wzp[2*j+1]), h1, az, false);
      an = __builtin_amdgcn_fdot2(u2h(wnp[2*j+1]), h1, an, false);
    }
#else
    #pragma unroll
    for (int j=0;j<16;j++){
      uint2 hw = *(const uint2*)(hrow + 2*j);
      f16x2 h0 = u2h(hw.x), h1 = u2h(hw.y);
      f16x2 wr0=u2h(wrp[2*j]), wr1=u2h(wrp[2*j+1]);
      f16x2 wz0=u2h(wzp[2*j]), wz1=u2h(wzp[2*j+1]);
      f16x2 wn0=u2h(wnp[2*j]), wn1=u2h(wnp[2*j+1]);
      ar = fmaf((float)wr0.x,(float)h0.x,ar); ar = fmaf((float)wr0.y,(float)h0.y,ar);
      ar = fmaf((float)wr1.x,(float)h1.x,ar); ar = fmaf((float)wr1.y,(float)h1.y,ar);
      az = fmaf((float)wz0.x,(float)h0.x,az); az = fmaf((float)wz0.y,(float)h0.y,az);
      az = fmaf((float)wz1.x,(float)h1.x,az); az = fmaf((float)wz1.y,(float)h1.y,az);
      an = fmaf((float)wn0.x,(float)h0.x,an); an = fmaf((float)wn0.y,(float)h0.y,an);
      an = fmaf((float)wn1.x,(float)h1.x,an); an = fmaf((float)wn1.y,(float)h1.y,an);
    }
#endif
    #pragma unroll
    for (int off=1; off<16; off<<=1){
      ar += __shfl_xor(ar, off);
      az += __shfl_xor(az, off);
      an += __shfl_xor(an, off);
    }

    if (ks == 0){
      float r = sigmoidf_(xr_c + ar + bhr);
      float z = sigmoidf_(xzg_c + az + bhz);
      float n = tanhf_(xn_c + r*(an + bhn));
      float hnew  = (1.f - z)*n + z*hprev;
      hprev = hnew;
      unsigned long long packed = (unsigned long long)f2bits(hnew)
                                | (((unsigned long long)(lbase + (uint32_t)t + 1u)) << 32);
      const uintptr_t hdst = (uintptr_t)(hbuf + ((size_t)((t+1)&1)*NB + b)*DI + i);
      asm volatile("global_store_dwordx2 %0, %1, off sc0 sc1"
                   :: "v"(hdst), "v"(packed) : "memory");
      const size_t rowx = (size_t)(b*SEQ + t);
      xout[rowx*DI + i] = f2bf(hnew * siluf_(zg_c));
      xr_c = xr_n; xzg_c = xzg_n; xn_c = xn_n; zg_c = zg_n;
    }
  }
}

// ---------------- host ----------------
extern "C" void kernel_launch(void* const* d_in, const int* in_sizes, int n_in,
                              void* d_out, int out_size, void* d_ws, size_t ws_size,
                              hipStream_t stream)
{
  (void)in_sizes; (void)n_in; (void)out_size; (void)ws_size;
  const float* x      = (const float*)d_in[0];
  const float* norm_w = (const float*)d_in[1];
  const float* norm_b = (const float*)d_in[2];
  const float* inw    = (const float*)d_in[3];
  const float* inb    = (const float*)d_in[4];
  const float* convw  = (const float*)d_in[5];
  const float* convb  = (const float*)d_in[6];
  const float* wih    = (const float*)d_in[7];
  const float* whh    = (const float*)d_in[8];
  const float* bih    = (const float*)d_in[9];
  const float* bhh    = (const float*)d_in[10];
  const float* outw   = (const float*)d_in[11];
  const float* outb   = (const float*)d_in[12];
  const float* normfw = (const float*)d_in[13];
  const float* normfb = (const float*)d_in[14];
  float* out = (float*)d_out;

  char* ws = (char*)d_ws;
  size_t off = 0;
  auto alloc = [&](size_t bytes)->void*{ void* p = ws + off; off = (off + bytes + 255) & ~(size_t)255; return p; };
  float*          resid  = (float*)         alloc((size_t)BT*DM*4);
  unsigned short* lnbf   = (unsigned short*)alloc((size_t)BT*DM*2);
  float*          xz     = (float*)         alloc((size_t)BT*2*DI*4);
  unsigned short* xconv  = (unsigned short*)alloc((size_t)BT*DI*2);
  unsigned short* xihb   = (unsigned short*)alloc((size_t)BT*3*DI*2);
  unsigned short* xoutb  = (unsigned short*)alloc((size_t)BT*DI*2);
  float*          hidden = (float*)         alloc((size_t)BT*DM*4);
  unsigned short* w1bf   = (unsigned short*)alloc((size_t)2048*512*2);
  unsigned short* wihbf  = (unsigned short*)alloc((size_t)3072*1024*2);
  unsigned short* whh16  = (unsigned short*)alloc((size_t)3072*1024*2);
  unsigned short* woutbf = (unsigned short*)alloc((size_t)512*1024*2);
  unsigned long long* hbuf = (unsigned long long*)alloc((size_t)2*NB*DI*8);

  hipMemsetAsync(hbuf, 0, (size_t)2*NB*DI*8, stream);

  const float* hid_in = x;
  const float* res_in = nullptr;
  for (int l = 0; l < 6; ++l){
    ln_kernel<<<1024, 256, 0, stream>>>(hid_in, res_in, norm_w + l*DM, norm_b + l*DM,
                                        resid, lnbf, nullptr);
    cvt_kernel<<<2048, 256, 0, stream>>>(inw  + (size_t)l*2048*512,  w1bf,   2048*512);
    cvt_kernel<<<2048, 256, 0, stream>>>(wih  + (size_t)l*3072*1024, wihbf,  3072*1024);
    cvt16_kernel<<<2048, 256, 0, stream>>>(whh + (size_t)l*3072*1024, whh16, 3072*1024);
    cvt_kernel<<<2048, 256, 0, stream>>>(outw + (size_t)l*512*1024,  woutbf, 512*1024);
    // in_proj: xz = ln * inw^T + inb   [4096 x 2048], fp32 out
    gemm_kernel<<<dim3(2048/128, BT/128), 256, 0, stream>>>(lnbf, w1bf, inb + l*2048,
                                                            xz, nullptr, BT, 2048, 512);
    conv_silu_kernel<<<(BT*DI)/256, 256, 0, stream>>>(xz, convw + (size_t)l*DI*4,
                                                      convb + (size_t)l*DI, xconv);
    // gru input: xih = xconv * wih^T + bih  [4096 x 3072], bf16 out
    gemm_kernel<<<dim3(3072/128, BT/128), 256, 0, stream>>>(xconv, wihbf, bih + l*3072,
                                                            nullptr, xihb, BT, 3072, 1024);
    scan_kernel<<<256, 256, 0, stream>>>(xihb, xz, whh16, bhh + l*3072, hbuf, xoutb, l);
    // out proj: hidden = xout * outw^T + outb  [4096 x 512], fp32 out
    gemm_kernel<<<dim3(512/128, BT/128), 256, 0, stream>>>(xoutb, woutbf, outb + l*DM,
                                                           hidden, nullptr, BT, 512, 1024);
    hid_in = hidden; res_in = resid;
  }
  ln_kernel<<<1024, 256, 0, stream>>>(hidden, resid, normfw, normfb,
                                      nullptr, nullptr, out);
}